// Round 3
// baseline (1439.939 us; speedup 1.0000x reference)
//
#include <hip/hip_runtime.h>
#include <math.h>

namespace {

constexpr int Bb = 16;
constexpr int TQ = 2048;
constexpr int TK = 2048;
constexpr int D  = 1024;

typedef __bf16 bf16x8 __attribute__((ext_vector_type(8)));
typedef float  f32x4  __attribute__((ext_vector_type(4)));
typedef unsigned short u16;
typedef unsigned int   u32;
typedef u16 u16x8 __attribute__((ext_vector_type(8)));

typedef __attribute__((address_space(1))) const unsigned char gbyte;
typedef __attribute__((address_space(3))) unsigned char sbyte;

__device__ inline u16 f2bf(float f) {
    u32 u = __builtin_bit_cast(u32, f);
    u += 0x7fffu + ((u >> 16) & 1u);          // round-to-nearest-even
    return (u16)(u >> 16);
}
__device__ inline float bf2f(u16 h) {
    u32 u = (u32)h << 16;
    return __builtin_bit_cast(float, u);
}
__device__ inline void split1(float f, u16& h, u16& l) {
    h = f2bf(f);
    l = f2bf(f - bf2f(h));
}

__device__ inline void gload16(const void* g, void* l) {
    __builtin_amdgcn_global_load_lds((gbyte*)g, (sbyte*)l, 16, 0, 0);
}

#define MFMA16(d, a, b) d = __builtin_amdgcn_mfma_f32_16x16x32_bf16(a, b, d, 0, 0, 0)

// ---------------------------------------------------------------------------
// Ring-4 deep-pipelined NT GEMM: C[m][n] = sum_k A[m][k]*B[n][k], bf16 in.
// 256x256 tile, BK=32, 512 thr = 8 waves (2M x 4N), wave owns 128x64 out.
// LDS: ring of 4 K-tiles, each (A[256][32] | B[256][32]) bf16 = 32 KiB,
// total 128 KiB.  While computing tile t, stage tile t+3 (slot (t+3)&3 =
// (t-1)&3, freed by the barrier at end of tile t-1).  Issue-to-wait
// distance = 3 tiles (~6 phases) -> HBM-miss latency (~900cy) fully hidden
// (round-2's double buffer gave late loads only ~150cy slack -> 47% util).
// Per tile: 2 phases {ds_read frags | issue 2 global_load_lds -> s_barrier
// -> lgkmcnt(0) -> setprio(1) -> 16 MFMA -> setprio(0) -> [vmcnt] barrier}.
// Tile-boundary wait vmcnt(8): oldest 4 loads (tile t+1's) retired; 8 stay
// in flight.  Tail: vmcnt(4), vmcnt(0), none.
// Rows are 32 bf16 = 4 x 16B slots; physical slot = lq ^ ((row>>1)&3),
// realized by pre-swizzling the GLOBAL source (LDS dest linear, as
// global_load_lds requires) and the same XOR on the ds_read address.
// Conflict-free within 8-lane b128 service groups:
// (row&1)*64 + 16*((row>>1)&3) is bijective over 8 consecutive rows.
// SEGS==3: bf16x3 product, K-space = 3 segments over [M][2K]/[N][2K]:
//   seg0 Ah*Bh (0,0)  seg1 Ah*Bl (0,K)  seg2 Al*Bh (K,0)
// EPI==0: fp32 store.  EPI==1: split h/l store into C2 [M][2N].
// Grid is XCD-swizzled (T1): flat ids chunked 8 ways (nwg%8==0 for all
// uses) so each XCD's L2 sees contiguous batches/panels.
// ---------------------------------------------------------------------------
template<bool STAGE, int VM>
__device__ __attribute__((always_inline))
void do_tile32(const char* buf, char* sA, char* sB,
               const u16* aP, const u16* bP, long long ldH,
               int aRd, int bRd, f32x4 (&acc)[8][4])
{
    bf16x8 A0, A1, A2, A3, B0, B1, B2, B3;

    // ===== phase 0: read A(mt0-3) + B(nt0-3); stage A of tile t+3 =====
    A0 = *(const bf16x8*)(buf + aRd);
    A1 = *(const bf16x8*)(buf + aRd + 1024);
    A2 = *(const bf16x8*)(buf + aRd + 2048);
    A3 = *(const bf16x8*)(buf + aRd + 3072);
    B0 = *(const bf16x8*)(buf + bRd);
    B1 = *(const bf16x8*)(buf + bRd + 1024);
    B2 = *(const bf16x8*)(buf + bRd + 2048);
    B3 = *(const bf16x8*)(buf + bRd + 3072);
    if constexpr (STAGE) {
        gload16(aP,       sA);           // A rows   0-127
        gload16(aP + ldH, sA + 8192);    // A rows 128-255
    }
    __builtin_amdgcn_s_barrier();
    asm volatile("s_waitcnt lgkmcnt(0)" ::: "memory");
    __builtin_amdgcn_s_setprio(1);
    MFMA16(acc[0][0], A0, B0); MFMA16(acc[0][1], A0, B1);
    MFMA16(acc[0][2], A0, B2); MFMA16(acc[0][3], A0, B3);
    MFMA16(acc[1][0], A1, B0); MFMA16(acc[1][1], A1, B1);
    MFMA16(acc[1][2], A1, B2); MFMA16(acc[1][3], A1, B3);
    MFMA16(acc[2][0], A2, B0); MFMA16(acc[2][1], A2, B1);
    MFMA16(acc[2][2], A2, B2); MFMA16(acc[2][3], A2, B3);
    MFMA16(acc[3][0], A3, B0); MFMA16(acc[3][1], A3, B1);
    MFMA16(acc[3][2], A3, B2); MFMA16(acc[3][3], A3, B3);
    __builtin_amdgcn_s_setprio(0);
    __builtin_amdgcn_s_barrier();

    // ===== phase 1: read A(mt4-7); stage B of tile t+3 =====
    A0 = *(const bf16x8*)(buf + aRd + 4096);
    A1 = *(const bf16x8*)(buf + aRd + 5120);
    A2 = *(const bf16x8*)(buf + aRd + 6144);
    A3 = *(const bf16x8*)(buf + aRd + 7168);
    if constexpr (STAGE) {
        gload16(bP,       sB);           // B rows   0-127
        gload16(bP + ldH, sB + 8192);    // B rows 128-255
    }
    __builtin_amdgcn_s_barrier();
    asm volatile("s_waitcnt lgkmcnt(0)" ::: "memory");
    __builtin_amdgcn_s_setprio(1);
    MFMA16(acc[4][0], A0, B0); MFMA16(acc[4][1], A0, B1);
    MFMA16(acc[4][2], A0, B2); MFMA16(acc[4][3], A0, B3);
    MFMA16(acc[5][0], A1, B0); MFMA16(acc[5][1], A1, B1);
    MFMA16(acc[5][2], A1, B2); MFMA16(acc[5][3], A1, B3);
    MFMA16(acc[6][0], A2, B0); MFMA16(acc[6][1], A2, B1);
    MFMA16(acc[6][2], A2, B2); MFMA16(acc[6][3], A2, B3);
    MFMA16(acc[7][0], A3, B0); MFMA16(acc[7][1], A3, B1);
    MFMA16(acc[7][2], A3, B2); MFMA16(acc[7][3], A3, B3);
    __builtin_amdgcn_s_setprio(0);
    if constexpr (VM == 8)      asm volatile("s_waitcnt vmcnt(8)" ::: "memory");
    else if constexpr (VM == 4) asm volatile("s_waitcnt vmcnt(4)" ::: "memory");
    else if constexpr (VM == 0) asm volatile("s_waitcnt vmcnt(0)" ::: "memory");
    __builtin_amdgcn_s_barrier();
}

template<int SEGS, int EPI>
__global__ __launch_bounds__(512, 2)
void gemm_nt_pipe(const u16* __restrict__ A, const u16* __restrict__ B,
                  float* __restrict__ Cf, u16* __restrict__ C2,
                  int M, int N, int K,
                  long long sA, long long sB, long long sC)
{
    __shared__ char lds[131072];   // ring of 4 x (A 16K | B 16K)

    // ---- XCD-aware block remap (nwg % 8 == 0 for all launches) ----
    int bx = blockIdx.x, by = blockIdx.y, bz = blockIdx.z;
    {
        const int gx = gridDim.x, gy = gridDim.y;
        const int nwg = gx * gy * (int)gridDim.z;
        const int flat = bx + gx * (by + gy * bz);
        const int q = nwg >> 3;
        int s = (flat & 7) * q + (flat >> 3);
        bx = s % gx; s /= gx;
        by = s % gy; bz = s / gy;
    }

    const int tid  = threadIdx.x;
    const int lane = tid & 63;
    const int wave = tid >> 6;
    const int wm   = wave >> 2;            // 0..1  (M half)
    const int wn   = wave & 3;             // 0..3  (N quarter)
    const int lr   = lane & 15;
    const int lq   = lane >> 4;

    const int n0 = bx * 256;
    const int m0 = by * 256;

    const int ld = (SEGS == 3) ? 2 * K : K;     // row stride (elements)
    const long long ldH = (long long)128 * ld;  // 128-row advance

    const u16* Ab  = A + (long long)bz * sA;
    const u16* Bbp = B + (long long)bz * sB;

    // staging source: thread t -> row (t>>2), 16B slot (t&3)^((row>>1)&3)
    const int srow = tid >> 2;                        // 0..127
    const int scol = ((tid & 3) ^ ((tid >> 3) & 3)) * 8;
    const u16* aS = Ab  + (long long)(m0 + srow) * ld + scol;
    const u16* bS = Bbp + (long long)(n0 + srow) * ld + scol;

    // ds_read offsets: row*64 + swizzled slot*16
    const int swz = (lq ^ ((lr >> 1) & 3)) << 4;
    const int aRd = (wm * 128 + lr) * 64 + swz;
    const int bRd = 16384 + (wn * 64 + lr) * 64 + swz;

    f32x4 acc[8][4];
    #pragma unroll
    for (int i = 0; i < 8; ++i)
        #pragma unroll
        for (int j = 0; j < 4; ++j)
            acc[i][j] = (f32x4){0.f, 0.f, 0.f, 0.f};

    const int NT = (SEGS == 3 ? 3 * K : K) / 32;

    // ---- prologue: stage tiles 0,1,2 into slots 0,1,2 (12 loads) ----
    int kst = 0, seg = 0;                  // k-state of tile being staged
    #pragma unroll
    for (int p = 0; p < 3; ++p) {
        const int ao = kst + ((SEGS == 3 && seg == 2) ? K : 0);
        const int bo = kst + ((SEGS == 3 && seg == 1) ? K : 0);
        char* sl = lds + p * 32768;
        gload16(aS + ao,       sl + tid * 16);
        gload16(aS + ao + ldH, sl + 8192 + tid * 16);
        gload16(bS + bo,       sl + 16384 + tid * 16);
        gload16(bS + bo + ldH, sl + 24576 + tid * 16);
        kst += 32;
        if (SEGS == 3 && kst == K) { kst = 0; ++seg; }
    }
    asm volatile("s_waitcnt vmcnt(8)" ::: "memory");   // tile 0 landed
    __builtin_amdgcn_s_barrier();

    // ---- main: compute tile t from slot t&3, stage tile t+3 ----
    for (int t = 0; t < NT - 3; ++t) {
        const int ao = kst + ((SEGS == 3 && seg == 2) ? K : 0);
        const int bo = kst + ((SEGS == 3 && seg == 1) ? K : 0);
        const char* cb = lds + (t & 3) * 32768;
        char* nb = lds + ((t + 3) & 3) * 32768;
        do_tile32<true, 8>(cb, nb + tid * 16, nb + 16384 + tid * 16,
                           aS + ao, bS + bo, ldH, aRd, bRd, acc);
        kst += 32;
        if (SEGS == 3 && kst == K) { kst = 0; ++seg; }
    }
    do_tile32<false, 4>(lds + ((NT - 3) & 3) * 32768, nullptr, nullptr,
                        aS, bS, ldH, aRd, bRd, acc);
    do_tile32<false, 0>(lds + ((NT - 2) & 3) * 32768, nullptr, nullptr,
                        aS, bS, ldH, aRd, bRd, acc);
    do_tile32<false, -1>(lds + ((NT - 1) & 3) * 32768, nullptr, nullptr,
                         aS, bS, ldH, aRd, bRd, acc);

    // ---- epilogue: C/D layout row=(lane>>4)*4+reg, col=lane&15 ----
    if constexpr (EPI == 0) {
        #pragma unroll
        for (int mt = 0; mt < 8; ++mt) {
            const int row = m0 + wm * 128 + mt * 16 + lq * 4;
            #pragma unroll
            for (int nt = 0; nt < 4; ++nt) {
                const int col = n0 + wn * 64 + nt * 16 + lr;
                #pragma unroll
                for (int rg = 0; rg < 4; ++rg)
                    Cf[(long long)bz * sC + (long long)(row + rg) * N + col] =
                        acc[mt][nt][rg];
            }
        }
    } else {
        #pragma unroll
        for (int mt = 0; mt < 8; ++mt) {
            const int row = m0 + wm * 128 + mt * 16 + lq * 4;
            #pragma unroll
            for (int nt = 0; nt < 4; ++nt) {
                const int col = n0 + wn * 64 + nt * 16 + lr;
                #pragma unroll
                for (int rg = 0; rg < 4; ++rg) {
                    const long long base =
                        (long long)bz * sC + (long long)(row + rg) * (2 * N);
                    u16 h, l;
                    split1(acc[mt][nt][rg], h, l);
                    C2[base + col]     = h;
                    C2[base + N + col] = l;
                }
            }
        }
    }
}

// ---------------------------------------------------------------------------
// fp32 [R][1024] -> bf16 [R][2048]  (h in cols 0..1023, l in 1024..2047)
// ---------------------------------------------------------------------------
__global__ __launch_bounds__(256)
void split_rows(const float* __restrict__ in, u16* __restrict__ out)
{
    const long long i = (long long)blockIdx.x * 256 + threadIdx.x; // 8-chunk id
    const long long row = i >> 7;              // 128 chunks / row
    const int c = ((int)i & 127) << 3;
    const float* p = in + row * 1024 + c;
    float4 v0 = *(const float4*)p;
    float4 v1 = *(const float4*)(p + 4);
    float x[8] = {v0.x, v0.y, v0.z, v0.w, v1.x, v1.y, v1.z, v1.w};
    u16x8 h, l;
    #pragma unroll
    for (int j = 0; j < 8; ++j) {
        u16 hh, lo;
        split1(x[j], hh, lo);
        h[j] = hh; l[j] = lo;
    }
    u16* q = out + row * 2048 + c;
    *(u16x8*)q = h;
    *(u16x8*)(q + 1024) = l;
}

// ---------------------------------------------------------------------------
// Transpose fp32 [R][C] -> bf16 [C][R] (hi only). 32x32 tiles.
// ---------------------------------------------------------------------------
__global__ __launch_bounds__(256)
void transpose_h(const float* __restrict__ in, u16* __restrict__ outh,
                 int R, int C, long long sIn, long long sOut)
{
    __shared__ float t[32][33];
    const int bz = blockIdx.z;
    const int c0 = blockIdx.x * 32;
    const int r0 = blockIdx.y * 32;
    const float* inb = in + (long long)bz * sIn;
    const int tid = threadIdx.x;
    #pragma unroll
    for (int i = 0; i < 4; ++i) {
        int e = i * 256 + tid;
        int r = e >> 5, c = e & 31;
        t[r][c] = inb[(long long)(r0 + r) * C + c0 + c];
    }
    __syncthreads();
    #pragma unroll
    for (int i = 0; i < 4; ++i) {
        int e = i * 256 + tid;
        int r = e >> 5, c = e & 31;
        outh[(long long)bz * sOut + (long long)(c0 + r) * R + r0 + c] =
            f2bf(t[c][r]);
    }
}

// ---------------------------------------------------------------------------
// W [D][D] fp32 -> Wt2 [D][2D] bf16: h at [e][d], l at [e][D+d]
// ---------------------------------------------------------------------------
__global__ __launch_bounds__(256)
void transpose_split2(const float* __restrict__ in, u16* __restrict__ out2)
{
    __shared__ float t[32][33];
    const int c0 = blockIdx.x * 32;
    const int r0 = blockIdx.y * 32;
    const int tid = threadIdx.x;
    #pragma unroll
    for (int i = 0; i < 4; ++i) {
        int e = i * 256 + tid;
        int r = e >> 5, c = e & 31;
        t[r][c] = in[(long long)(r0 + r) * D + c0 + c];
    }
    __syncthreads();
    #pragma unroll
    for (int i = 0; i < 4; ++i) {
        int e = i * 256 + tid;
        int r = e >> 5, c = e & 31;
        u16 h, l;
        split1(t[c][r], h, l);
        const long long off = (long long)(c0 + r) * (2 * D) + r0 + c;
        out2[off]     = h;
        out2[off + D] = l;
    }
}

// ---------------------------------------------------------------------------
// Row softmax in place + bf16 copy: one block per row of TK floats.
// ---------------------------------------------------------------------------
__global__ __launch_bounds__(256)
void softmax_kernel(float* __restrict__ S, u16* __restrict__ Sb)
{
    __shared__ float red[4];
    const long long row = blockIdx.x;
    float* p = S + row * (long long)TK;
    const int tid = threadIdx.x;

    float x[8];
    *(float4*)&x[0] = *(const float4*)(p + tid * 8);
    *(float4*)&x[4] = *(const float4*)(p + tid * 8 + 4);

    float mx = x[0];
    #pragma unroll
    for (int i = 1; i < 8; ++i) mx = fmaxf(mx, x[i]);
    #pragma unroll
    for (int off = 32; off > 0; off >>= 1) mx = fmaxf(mx, __shfl_down(mx, off, 64));
    if ((tid & 63) == 0) red[tid >> 6] = mx;
    __syncthreads();
    mx = fmaxf(fmaxf(red[0], red[1]), fmaxf(red[2], red[3]));
    __syncthreads();

    float s = 0.f;
    #pragma unroll
    for (int i = 0; i < 8; ++i) { x[i] = __expf(x[i] - mx); s += x[i]; }
    #pragma unroll
    for (int off = 32; off > 0; off >>= 1) s += __shfl_down(s, off, 64);
    if ((tid & 63) == 0) red[tid >> 6] = s;
    __syncthreads();
    s = red[0] + red[1] + red[2] + red[3];

    const float inv = 1.f / s;
    #pragma unroll
    for (int i = 0; i < 8; ++i) x[i] *= inv;
    *(float4*)(p + tid * 8)     = *(const float4*)&x[0];
    *(float4*)(p + tid * 8 + 4) = *(const float4*)&x[4];

    u16x8 hb;
    #pragma unroll
    for (int i = 0; i < 8; ++i) hb[i] = f2bf(x[i]);
    *(u16x8*)(Sb + row * (long long)TK + tid * 8) = hb;
}

} // anonymous namespace

extern "C" void kernel_launch(void* const* d_in, const int* in_sizes, int n_in,
                              void* d_out, int out_size, void* d_ws, size_t ws_size,
                              hipStream_t stream)
{
    typedef long long ll;
    const float* dec = (const float*)d_in[0];  // [B, TQ, D]
    const float* enc = (const float*)d_in[1];  // [B, TK, D]
    const float* W   = (const float*)d_in[2];  // [D, D]
    // d_in[3] = bias: contributes dec[q].bias, constant along the softmax
    // axis -> cancels exactly in softmax; neither output depends on it.

    float* out     = (float*)d_out;
    float* context = out;                      // [B, TQ, D]
    float* align   = out + (ll)Bb * TQ * D;    // [B, TQ, TK]

    // workspace (u16): dec2 [B][TQ][2D] | keys2 [B][TK][2D] | Wt2 [D][2D]
    u16* dec2   = (u16*)d_ws;
    u16* keys2  = dec2 + (ll)Bb * TQ * 2 * D;
    u16* Wt2    = keys2 + (ll)Bb * TK * 2 * D;
    // scratch aliases (lifetimes verified against launch order):
    u16* enc2   = (u16*)align;   // enc split lives in align region until score
    u16* encT   = dec2;          // [B][D][TK]; dec2 dead after score
    u16* alignb = keys2;         // [B][TQ][TK] bf16; keys2 dead after score

    dim3 blk256(256);
    dim3 blk512(512);

    // 1) dec2 = split(dec)
    split_rows<<<dim3(Bb * TQ * D / 8 / 256), blk256, 0, stream>>>(dec, dec2);
    // 2) enc2 = split(enc)  (scratch in align output region)
    split_rows<<<dim3(Bb * TK * D / 8 / 256), blk256, 0, stream>>>(enc, enc2);
    // 3) Wt2 = split(W^T)
    transpose_split2<<<dim3(D / 32, D / 32, 1), blk256, 0, stream>>>(W, Wt2);
    // 4) keys2 = split(enc @ W)   (bf16x3, split-store epilogue)
    gemm_nt_pipe<3, 1><<<dim3(D / 256, TK / 256, Bb), blk512, 0, stream>>>(
        enc2, Wt2, nullptr, keys2, TK, D, D,
        (ll)TK * 2 * D, 0LL, (ll)TK * 2 * D);
    // 5) score = dec @ keys^T  (bf16x3) -> align region, fp32
    gemm_nt_pipe<3, 0><<<dim3(TK / 256, TQ / 256, Bb), blk512, 0, stream>>>(
        dec2, keys2, align, nullptr, TQ, TK, D,
        (ll)TQ * 2 * D, (ll)TK * 2 * D, (ll)TQ * TK);
    // 6) encT = enc^T bf16 (into dec2 space)
    transpose_h<<<dim3(D / 32, TK / 32, Bb), blk256, 0, stream>>>(
        enc, encT, TK, D, (ll)TK * D, (ll)D * TK);
    // 7) softmax in place + bf16 copy into alignb (keys2 space)
    softmax_kernel<<<dim3(Bb * TQ), blk256, 0, stream>>>(align, alignb);
    // 8) context = align @ enc  (plain bf16)
    gemm_nt_pipe<1, 0><<<dim3(D / 256, TQ / 256, Bb), blk512, 0, stream>>>(
        alignb, encT, context, nullptr, TQ, D, TK,
        (ll)TQ * TK, (ll)D * TK, (ll)TQ * D);
}